// Round 6
// baseline (69.908 us; speedup 1.0000x reference)
//
#include <hip/hip_runtime.h>

// ANFIS via MFMA, v6. B=32768, I=6, T=4, R=4096, C=[4096,7].
// r = h*64+l: w = PH[b,h]*PT[b,l]; num = PH^T * C2 * u, u[l*8+j]=PT[l]*xaug[j].
// GEMM V[b,n] = sum_c u[b,c]*B[c,n]; n<64: B=C2^T; in-reg indicator col gives
// V[b,64]=sumPT. den=(sum PH)*(sum PT)+1e-8.
// v6 vs v5: r5 had 2048 waves = 2 waves/SIMD -> stall-dominated (~18us vs
// ~2.5us of issue). K-SPLIT: each 16-row tile owned by a WAVE PAIR, each wave
// does 8 of 16 kt iters; partials combined via tiny LDS buffer. 1024 blocks x
// 4 waves = 4096 waves = 4/SIMD. Phase 1 split too (one wave PH, one PTT:
// 3 exps/row each). LDS ~18KB. MFMA layouts verified r4/r5:
// A[m=lane&15][k=q*8+j], B[k=q*8+j][n=lane&15], D: col=lane&15, row=q*4+reg.

typedef __attribute__((ext_vector_type(8))) short bf16x8;
typedef __attribute__((ext_vector_type(4))) float f32x4;

#define THREADS 256
#define BPB     32             // batch rows per block (16 per wave PAIR)
#define PH_STR  66             // fp32 words per PH row   [32][66]
#define PTT_STR 33             // fp32 words per PTT row  [64][33]

__device__ __forceinline__ unsigned int bf16rne(float f) {
    unsigned int u = __float_as_uint(f);
    u += 0x7fffu + ((u >> 16) & 1u);
    return u >> 16;
}

// ws4[l*64 + n] = 8 bf16 {C[n*64+l, 0..6], 0}
__global__ void anfis_prep(const float* __restrict__ cons, uint4* __restrict__ ws) {
    int id = blockIdx.x * blockDim.x + threadIdx.x;   // [0, 4096)
    if (id >= 4096) return;
    int l = id >> 6, n = id & 63;
    const float* src = cons + (n * 64 + l) * 7;
    unsigned int h[8];
#pragma unroll
    for (int j = 0; j < 7; ++j) h[j] = bf16rne(src[j]);
    h[7] = 0;
    uint4 v;
    v.x = h[0] | (h[1] << 16);
    v.y = h[2] | (h[3] << 16);
    v.z = h[4] | (h[5] << 16);
    v.w = h[6] | (h[7] << 16);
    ws[id] = v;
}

__launch_bounds__(THREADS, 4)
__global__ void anfis_mfma(const float* __restrict__ x,
                           const float* __restrict__ centers,
                           const float* __restrict__ sigmas,
                           const uint4* __restrict__ wsC,
                           float* __restrict__ out, int B) {
    __shared__ float  PH[BPB * PH_STR];        // [row 0..31][h 0..63]
    __shared__ float  PTT[64 * PTT_STR];       // [l 0..63][row 0..31]
    __shared__ float4 xs4[BPB * 6 / 4];        // 48 float4 = [32][6]
    __shared__ float  comb[2 * 4 * 8];         // pair-combine: [pair][q][Pn4,Pd4]

    const int tid  = threadIdx.x;
    const int lane = tid & 63;
    const int wv   = tid >> 6;                 // 0..3
    const int pairid = wv >> 1;                // 0..1 -> rows pairid*16..+15
    const int half   = wv & 1;                 // 0..1 -> kt half
    const long blockbase = (long)blockIdx.x * BPB;
    float* xs = (float*)xs4;

    // ---- stage this pair's 16 rows of x (both waves write same data; benign) ----
    if (lane < 24) {
        long idx4 = (long)blockIdx.x * 48 + pairid * 24 + lane;
        float4 v = (idx4 * 4 + 3 < (long)B * 6) ? ((const float4*)x)[idx4]
                                                : make_float4(0.f, 0.f, 0.f, 0.f);
        xs4[pairid * 24 + lane] = v;
    }

    // ---- phase 1: half==0 computes PH rows, half==1 computes PTT rows ----
    {
        const int d0 = (lane >> 4) & 3, d1 = (lane >> 2) & 3, d2 = lane & 3;
        const int ioff = half * 3;             // inputs 0-2 (PH) or 3-5 (PT)
        const int t3[3] = {d0, d1, d2};
        float cen[3], inv[3];
#pragma unroll
        for (int i = 0; i < 3; ++i) {
            cen[i] = centers[(ioff + i) * 4 + t3[i]];
            float s = fabsf(sigmas[(ioff + i) * 4 + t3[i]]) + 1e-6f;
            inv[i] = 0.5f / (s * s);
        }
#pragma unroll 4
        for (int g = 0; g < 16; ++g) {
            int bl = pairid * 16 + g;
            float m[3];
#pragma unroll
            for (int i = 0; i < 3; ++i) {
                float d = xs[bl * 6 + ioff + i] - cen[i];
                m[i] = __expf(-d * d * inv[i]);
            }
            float prod = m[0] * m[1] * m[2];
            if (half == 0) PH[bl * PH_STR + lane]   = prod;
            else           PTT[lane * PTT_STR + bl] = prod;
        }
    }
    __syncthreads();

    // ---- phase 2: wave does kt = half*8 .. half*8+7 for its pair's 16 rows ----
    const int t = lane & 15, q = lane >> 4, m0 = pairid * 16;

    float xa[8];
#pragma unroll
    for (int j = 0; j < 6; ++j) xa[j] = xs[(m0 + t) * 6 + j];
    xa[6] = 1.f;
    xa[7] = 0.f;

    union U4 { unsigned int u[4]; bf16x8 v; };
    U4 B4;                                     // indicator col: V[.,64] = sumPT
    B4.u[0] = B4.u[1] = B4.u[2] = 0u;
    B4.u[3] = (t == 0) ? 0x00003f80u : 0u;     // elem 6 = bf16(1.0) iff n==64

    f32x4 Dn[4], D4;
#pragma unroll
    for (int nt = 0; nt < 4; ++nt) Dn[nt] = (f32x4){0.f, 0.f, 0.f, 0.f};
    D4 = (f32x4){0.f, 0.f, 0.f, 0.f};

#pragma unroll 4
    for (int ktr = 0; ktr < 8; ++ktr) {
        const int kt = half * 8 + ktr;
        const int l  = kt * 4 + q;
        U4 Bf[4];
#pragma unroll
        for (int nt = 0; nt < 4; ++nt) {
            uint4 bw = wsC[l * 64 + nt * 16 + t];
            Bf[nt].u[0] = bw.x; Bf[nt].u[1] = bw.y;
            Bf[nt].u[2] = bw.z; Bf[nt].u[3] = bw.w;
        }
        float ptv = PTT[l * PTT_STR + m0 + t];
        U4 Ah, Al;
#pragma unroll
        for (int jp = 0; jp < 4; ++jp) {
            float u0 = ptv * xa[2 * jp];
            float u1 = ptv * xa[2 * jp + 1];
            unsigned int b0 = __float_as_uint(u0), b1 = __float_as_uint(u1);
            unsigned int t0 = b0 & 0xffff0000u, t1 = b1 & 0xffff0000u;
            float l0 = u0 - __uint_as_float(t0);
            float l1 = u1 - __uint_as_float(t1);
            Ah.u[jp] = (b0 >> 16) | t1;
            Al.u[jp] = (__float_as_uint(l0) >> 16) | (__float_as_uint(l1) & 0xffff0000u);
        }
#pragma unroll
        for (int nt = 0; nt < 4; ++nt)
            Dn[nt] = __builtin_amdgcn_mfma_f32_16x16x32_bf16(Ah.v, Bf[nt].v, Dn[nt], 0, 0, 0);
        D4 = __builtin_amdgcn_mfma_f32_16x16x32_bf16(Ah.v, B4.v, D4, 0, 0, 0);
#pragma unroll
        for (int nt = 0; nt < 4; ++nt)
            Dn[nt] = __builtin_amdgcn_mfma_f32_16x16x32_bf16(Al.v, Bf[nt].v, Dn[nt], 0, 0, 0);
        D4 = __builtin_amdgcn_mfma_f32_16x16x32_bf16(Al.v, B4.v, D4, 0, 0, 0);
    }

    // ---- epilogue: per-wave partials Pn/Pd (Ps is full sumPH in both waves) ----
    float Pn[4] = {0.f, 0.f, 0.f, 0.f};
    float Ps[4] = {0.f, 0.f, 0.f, 0.f};
    float Pd[4];
#pragma unroll
    for (int r = 0; r < 4; ++r) Pd[r] = D4[r];
#pragma unroll
    for (int nt = 0; nt < 4; ++nt)
#pragma unroll
        for (int r = 0; r < 4; ++r) {
            float phv = PH[(m0 + q * 4 + r) * PH_STR + nt * 16 + t];
            Pn[r] = fmaf(phv, Dn[nt][r], Pn[r]);
            Ps[r] += phv;
        }
#pragma unroll
    for (int off = 1; off < 16; off <<= 1)
#pragma unroll
        for (int r = 0; r < 4; ++r) {
            Pn[r] += __shfl_xor(Pn[r], off);
            Ps[r] += __shfl_xor(Ps[r], off);
            Pd[r] += __shfl_xor(Pd[r], off);
        }
    if (half == 1 && t == 0) {
#pragma unroll
        for (int r = 0; r < 4; ++r) {
            comb[pairid * 32 + q * 8 + r]     = Pn[r];
            comb[pairid * 32 + q * 8 + 4 + r] = Pd[r];
        }
    }
    __syncthreads();
    if (half == 0 && t == 0) {
        long bo = blockbase + m0 + q * 4;
        float o[4];
#pragma unroll
        for (int r = 0; r < 4; ++r) {
            float n2 = Pn[r] + comb[pairid * 32 + q * 8 + r];
            float d2 = Pd[r] + comb[pairid * 32 + q * 8 + 4 + r];
            o[r] = n2 / (Ps[r] * d2 + 1e-8f);
        }
        if (bo + 3 < B) {
            *(float4*)&out[bo] = make_float4(o[0], o[1], o[2], o[3]);
        } else {
#pragma unroll
            for (int r = 0; r < 4; ++r)
                if (bo + r < B) out[bo + r] = o[r];
        }
    }
}

extern "C" void kernel_launch(void* const* d_in, const int* in_sizes, int n_in,
                              void* d_out, int out_size, void* d_ws, size_t ws_size,
                              hipStream_t stream) {
    const float* x       = (const float*)d_in[0];
    const float* centers = (const float*)d_in[1];
    const float* sigmas  = (const float*)d_in[2];
    const float* cons    = (const float*)d_in[3];
    float* out = (float*)d_out;

    int B = in_sizes[0] / 6;                       // 32768
    uint4* wsC = (uint4*)d_ws;                     // needs 65536 B

    anfis_prep<<<16, 256, 0, stream>>>(cons, wsC);
    int blocks = (B + BPB - 1) / BPB;              // 1024
    anfis_mfma<<<blocks, THREADS, 0, stream>>>(x, centers, sigmas, wsC, out, B);
}

// Round 7
// 69.200 us; speedup vs baseline: 1.0102x; 1.0102x over previous
//
#include <hip/hip_runtime.h>

// ANFIS via MFMA, v7 — SINGLE KERNEL. B=32768, I=6, T=4, R=4096, C=[4096,7].
// r = h*64+l: w = PH[b,h]*PT[b,l]; num = PH^T * C2 * u, u[l*8+j]=PT[l]*xaug[j].
// GEMM V[b,n] = sum_c u[b,c]*Bm[c,n] (Bm = C2^T, bf16), num = sum_n PH*V,
// den = prod_i (sum_t E[i][t]) (fully separable, computed per-lane).
// v7 vs v6: r5/r6 identical dur (~70) despite 2x occupancy change => total is
// floor-bound by harness fill (~40us) + per-node launch overhead, not kernel
// math. So: (1) prep kernel merged in (one graph node), (2) memberships fully
// register-resident via digit separability (l=kt*4+q => digits kt>>2, kt&3, q
// are unroll-constant), (3) denominator local (no indicator MFMA, no Ps
// reduce), (4) C packed to LDS [l][n] stride-65 uint4 (conflict-free b128).
// MFMA 16x16x32 bf16 layouts (verified r4-r6): A[m=lane&15][k=q*8+j],
// B[k=q*8+j][n=lane&15], D: col=lane&15, row=q*4+reg (q=lane>>4).

typedef __attribute__((ext_vector_type(8))) short bf16x8;
typedef __attribute__((ext_vector_type(4))) float f32x4;

#define THREADS 256
#define TAB_STR 65                        // uint4 slots per l-row (64 + 1 pad)
#define TAB_BYTES (64 * TAB_STR * 16)     // 66560

__device__ __forceinline__ unsigned int bf16rne(float f) {
    unsigned int u = __float_as_uint(f);
    u += 0x7fffu + ((u >> 16) & 1u);
    return u >> 16;
}

__device__ __forceinline__ float sel4(float a0, float a1, float a2, float a3, int i) {
    float lo = (i & 1) ? a1 : a0;
    float hi = (i & 1) ? a3 : a2;
    return (i & 2) ? hi : lo;
}

extern __shared__ uint4 tab[];            // [l 0..63][n 0..63] + pad, bf16x8 rows

__launch_bounds__(THREADS, 2)
__global__ void anfis_one(const float* __restrict__ x,
                          const float* __restrict__ centers,
                          const float* __restrict__ sigmas,
                          const float* __restrict__ cons,
                          float* __restrict__ out, int B) {
    __shared__ float4 xs4[96];            // [64 rows][6] floats
    float* xs = (float*)xs4;

    const int tid  = threadIdx.x;
    const int lane = tid & 63;
    const int wv   = tid >> 6;            // wave 0..3, rows wv*16..+15
    const long blockbase = (long)blockIdx.x * 64;

    // ---- stage x: 96 float4 per block, wave-local rows ----
    if (lane < 24) {
        long i4 = (long)blockIdx.x * 96 + wv * 24 + lane;
        float4 v = (i4 * 4 + 3 < (long)B * 6) ? ((const float4*)x)[i4]
                                              : make_float4(0.f, 0.f, 0.f, 0.f);
        xs4[wv * 24 + lane] = v;
    }

    // ---- stage packed C table: 16 rules/thread, r = n*64 + lane ----
    // reads: lane-consecutive r -> 1792 B contiguous per wave (L2-hot)
    // writes: tab[lane*65 + n] -> stride-65 pad = conflict-free b128
#pragma unroll 4
    for (int i = 0; i < 16; ++i) {
        int n = wv + 4 * i;
        const float* src = cons + (n * 64 + lane) * 7;
        unsigned int h0 = bf16rne(src[0]), h1 = bf16rne(src[1]);
        unsigned int h2 = bf16rne(src[2]), h3 = bf16rne(src[3]);
        unsigned int h4 = bf16rne(src[4]), h5 = bf16rne(src[5]);
        unsigned int h6 = bf16rne(src[6]);
        uint4 v;
        v.x = h0 | (h1 << 16);
        v.y = h2 | (h3 << 16);
        v.z = h4 | (h5 << 16);
        v.w = h6;
        tab[lane * TAB_STR + n] = v;
    }

    // ---- memberships: all in registers (xs is wave-local; no barrier yet) ----
    const int t = lane & 15, q = lane >> 4;
    const int lmA = wv * 16 + t;          // this lane's A-frag / PT / den row

    float cenv[6][4], invv[6][4];
#pragma unroll
    for (int i = 0; i < 6; ++i)
#pragma unroll
        for (int tm = 0; tm < 4; ++tm) {
            cenv[i][tm] = centers[i * 4 + tm];
            float s = fabsf(sigmas[i * 4 + tm]) + 1e-6f;
            invv[i][tm] = 0.5f / (s * s);
        }

    float xA[6];
#pragma unroll
    for (int j = 0; j < 6; ++j) xA[j] = xs[lmA * 6 + j];

    float E[6][4];
#pragma unroll
    for (int i = 0; i < 6; ++i)
#pragma unroll
        for (int tm = 0; tm < 4; ++tm) {
            float d = xA[i] - cenv[i][tm];
            E[i][tm] = __expf(-d * d * invv[i][tm]);
        }
    float den_local = (E[0][0] + E[0][1] + E[0][2] + E[0][3])
                    * (E[1][0] + E[1][1] + E[1][2] + E[1][3])
                    * (E[2][0] + E[2][1] + E[2][2] + E[2][3])
                    * (E[3][0] + E[3][1] + E[3][2] + E[3][3])
                    * (E[4][0] + E[4][1] + E[4][2] + E[4][3])
                    * (E[5][0] + E[5][1] + E[5][2] + E[5][3]);

    float e5q = sel4(E[5][0], E[5][1], E[5][2], E[5][3], q);
    float pt16[16];
#pragma unroll
    for (int kt = 0; kt < 16; ++kt)
        pt16[kt] = E[3][kt >> 2] * E[4][kt & 3] * e5q;   // digits: kt>>2, kt&3, q

    // PH[row=wv*16+q*4+r][h=nt*16+t]: digits (nt, t>>2, t&3)
    float PH16[4][4];
    {
        const int tm1 = t >> 2, tm2 = t & 3;
        float c1 = sel4(cenv[1][0], cenv[1][1], cenv[1][2], cenv[1][3], tm1);
        float i1 = sel4(invv[1][0], invv[1][1], invv[1][2], invv[1][3], tm1);
        float c2 = sel4(cenv[2][0], cenv[2][1], cenv[2][2], cenv[2][3], tm2);
        float i2 = sel4(invv[2][0], invv[2][1], invv[2][2], invv[2][3], tm2);
#pragma unroll
        for (int r = 0; r < 4; ++r) {
            int lr = wv * 16 + q * 4 + r;
            float x0 = xs[lr * 6 + 0];
            float x1 = xs[lr * 6 + 1];
            float x2 = xs[lr * 6 + 2];
            float d1 = x1 - c1, d2 = x2 - c2;
            float G12 = __expf(-d1 * d1 * i1) * __expf(-d2 * d2 * i2);
#pragma unroll
            for (int nt = 0; nt < 4; ++nt) {
                float d0 = x0 - cenv[0][nt];
                PH16[r][nt] = G12 * __expf(-d0 * d0 * invv[0][nt]);
            }
        }
    }

    float xa[8];
#pragma unroll
    for (int j = 0; j < 6; ++j) xa[j] = xA[j];
    xa[6] = 1.f;
    xa[7] = 0.f;

    __syncthreads();                      // tab ready (cross-wave n coverage)

    // ---- GEMM: V[16][64] = U[16][512] @ Bm[512][64], K tiled by kt ----
    union U4 { unsigned int u[4]; bf16x8 v; };
    f32x4 Dn[4];
#pragma unroll
    for (int nt = 0; nt < 4; ++nt) Dn[nt] = (f32x4){0.f, 0.f, 0.f, 0.f};

#pragma unroll 4
    for (int kt = 0; kt < 16; ++kt) {
        const uint4* base = &tab[(kt * 4 + q) * TAB_STR + t];
        U4 Bf[4];
#pragma unroll
        for (int nt = 0; nt < 4; ++nt) {
            uint4 bw = base[nt * 16];     // conflict-at-floor b128
            Bf[nt].u[0] = bw.x; Bf[nt].u[1] = bw.y;
            Bf[nt].u[2] = bw.z; Bf[nt].u[3] = bw.w;
        }
        float ptv = pt16[kt];
        U4 Ah, Al;
#pragma unroll
        for (int jp = 0; jp < 4; ++jp) {
            float u0 = ptv * xa[2 * jp];
            float u1 = ptv * xa[2 * jp + 1];
            unsigned int b0 = __float_as_uint(u0), b1 = __float_as_uint(u1);
            unsigned int t0 = b0 & 0xffff0000u, t1 = b1 & 0xffff0000u;
            float l0 = u0 - __uint_as_float(t0);
            float l1 = u1 - __uint_as_float(t1);
            Ah.u[jp] = (b0 >> 16) | t1;
            Al.u[jp] = (__float_as_uint(l0) >> 16) | (__float_as_uint(l1) & 0xffff0000u);
        }
#pragma unroll
        for (int nt = 0; nt < 4; ++nt)
            Dn[nt] = __builtin_amdgcn_mfma_f32_16x16x32_bf16(Ah.v, Bf[nt].v, Dn[nt], 0, 0, 0);
#pragma unroll
        for (int nt = 0; nt < 4; ++nt)
            Dn[nt] = __builtin_amdgcn_mfma_f32_16x16x32_bf16(Al.v, Bf[nt].v, Dn[nt], 0, 0, 0);
    }

    // ---- epilogue: Pn[r] = sum_n PH*V (t-reduction); den via 4 shuffles ----
    float Pn[4] = {0.f, 0.f, 0.f, 0.f};
#pragma unroll
    for (int nt = 0; nt < 4; ++nt)
#pragma unroll
        for (int r = 0; r < 4; ++r)
            Pn[r] = fmaf(PH16[r][nt], Dn[nt][r], Pn[r]);
#pragma unroll
    for (int off = 1; off < 16; off <<= 1)
#pragma unroll
        for (int r = 0; r < 4; ++r)
            Pn[r] += __shfl_xor(Pn[r], off);

    float dq[4];
#pragma unroll
    for (int r = 0; r < 4; ++r)
        dq[r] = __shfl(den_local, q * 4 + r);   // den for row wv*16+q*4+r

    if (t == 0) {
        long bo = blockbase + wv * 16 + q * 4;
        float o[4];
#pragma unroll
        for (int r = 0; r < 4; ++r) o[r] = Pn[r] / (dq[r] + 1e-8f);
        if (bo + 3 < B) {
            *(float4*)&out[bo] = make_float4(o[0], o[1], o[2], o[3]);
        } else {
#pragma unroll
            for (int r = 0; r < 4; ++r)
                if (bo + r < B) out[bo + r] = o[r];
        }
    }
}

extern "C" void kernel_launch(void* const* d_in, const int* in_sizes, int n_in,
                              void* d_out, int out_size, void* d_ws, size_t ws_size,
                              hipStream_t stream) {
    const float* x       = (const float*)d_in[0];
    const float* centers = (const float*)d_in[1];
    const float* sigmas  = (const float*)d_in[2];
    const float* cons    = (const float*)d_in[3];
    float* out = (float*)d_out;

    int B = in_sizes[0] / 6;                       // 32768
    hipFuncSetAttribute(reinterpret_cast<const void*>(anfis_one),
                        hipFuncAttributeMaxDynamicSharedMemorySize, TAB_BYTES);
    int blocks = (B + 63) / 64;                    // 512
    anfis_one<<<blocks, THREADS, TAB_BYTES, stream>>>(x, centers, sigmas, cons,
                                                      out, B);
}

// Round 9
// 68.181 us; speedup vs baseline: 1.0253x; 1.0149x over previous
//
#include <hip/hip_runtime.h>

// ANFIS via MFMA, v8b — single kernel, fp16 GEMM. B=32768, I=6, T=4, R=4096.
// r = h*64+l: w = PH[b,h]*PT[b,l]; num = PH^T * C2 * u, u[l*8+j]=PT[l]*xaug[j].
// V[b,n] = sum_c u[b,c]*Bm[c,n] (Bm=C2^T fp16), num = sum_n PH*V,
// den = prod_i (sum_t E[i][t]) (separable, per-lane in registers).
// v8 vs v7 (69.2us total; r5/r6/r7 within 0.7us of each other):
//  - fp16 (2^-10 RTZ) replaces bf16 hi/lo split: 64 MFMAs/wave (was 128),
//    A-pack = 4 cvt_pkrtz/kt (was ~20 VALU)
//  - C pack: 28 dwordx4 loads/thread (was 112 scalar dwords) - thread owns 16
//    consecutive rules; n = tid>>2 fixed, l = (tid&3)*16+k
//  - 8 accumulators (kt parity) to relax MFMA same-acc dependency distance
// v8b: fix cvt_pkrtz return-type mismatch (__fp16 vec2, not _Float16 vec2).
// If this round doesn't move dur, the 69us is harness floor (fill 40us + fixed
// node residue) and the kernel is already ~4us -> roofline.
// MFMA 16x16x32 layouts (dtype-indep, verified r4-r7): A[m=lane&15][k=q*8+j],
// B[k=q*8+j][n=lane&15], D: col=lane&15, row=q*4+reg (q=lane>>4).

typedef __attribute__((ext_vector_type(8))) _Float16 f16x8;
typedef __attribute__((ext_vector_type(4))) float f32x4;

#define THREADS 256
#define TAB_STR 65                        // uint4 slots per l-row (64 + 1 pad)
#define TAB_BYTES (64 * TAB_STR * 16)     // 66560

__device__ __forceinline__ unsigned int pkh(float a, float b) {
    union { __fp16 h __attribute__((ext_vector_type(2))); unsigned int u; } z;
    z.h = __builtin_amdgcn_cvt_pkrtz(a, b);   // a->low half, b->high half
    return z.u;
}

__device__ __forceinline__ float sel4(float a0, float a1, float a2, float a3, int i) {
    float lo = (i & 1) ? a1 : a0;
    float hi = (i & 1) ? a3 : a2;
    return (i & 2) ? hi : lo;
}

extern __shared__ uint4 tab[];            // [l 0..63][n 0..63] + pad, f16x8 rows

__launch_bounds__(THREADS, 2)
__global__ void anfis_one(const float* __restrict__ x,
                          const float* __restrict__ centers,
                          const float* __restrict__ sigmas,
                          const float* __restrict__ cons,
                          float* __restrict__ out, int B) {
    __shared__ float4 xs4[96];            // [64 rows][6] floats
    float* xs = (float*)xs4;

    const int tid  = threadIdx.x;
    const int lane = tid & 63;
    const int wv   = tid >> 6;            // wave 0..3, rows wv*16..+15
    const long blockbase = (long)blockIdx.x * 64;

    // ---- stage x: 96 float4 per block, wave-local rows ----
    if (lane < 24) {
        long i4 = (long)blockIdx.x * 96 + wv * 24 + lane;
        float4 v = (i4 * 4 + 3 < (long)B * 6) ? ((const float4*)x)[i4]
                                              : make_float4(0.f, 0.f, 0.f, 0.f);
        xs4[wv * 24 + lane] = v;
    }

    // ---- pack C -> fp16 tab. Thread owns rules [tid*16, tid*16+16):
    //      n = tid>>2 (fixed), l = (tid&3)*16 + k. 7 float4 loads per 4 rules.
    {
        const float4* cons4 = (const float4*)cons;
        const int base4 = tid * 28;           // 7168 float4 total, exact cover
        const int n     = tid >> 2;
        const int lbase = (tid & 3) * 16;
#pragma unroll
        for (int i = 0; i < 4; ++i) {
            float F[28];
            float4* Fv = (float4*)F;
#pragma unroll
            for (int j = 0; j < 7; ++j) Fv[j] = cons4[base4 + i * 7 + j];
#pragma unroll
            for (int m = 0; m < 4; ++m) {
                uint4 v;
                v.x = pkh(F[m * 7 + 0], F[m * 7 + 1]);
                v.y = pkh(F[m * 7 + 2], F[m * 7 + 3]);
                v.z = pkh(F[m * 7 + 4], F[m * 7 + 5]);
                v.w = pkh(F[m * 7 + 6], 0.f);
                tab[(lbase + i * 4 + m) * TAB_STR + n] = v;
            }
        }
    }

    // ---- memberships: all in registers (xs is wave-local; no barrier yet) ----
    const int t = lane & 15, q = lane >> 4;
    const int lmA = wv * 16 + t;          // this lane's A-frag / PT / den row

    float cenv[6][4], invv[6][4];
#pragma unroll
    for (int i = 0; i < 6; ++i)
#pragma unroll
        for (int tm = 0; tm < 4; ++tm) {
            cenv[i][tm] = centers[i * 4 + tm];
            float s = fabsf(sigmas[i * 4 + tm]) + 1e-6f;
            invv[i][tm] = 0.5f / (s * s);
        }

    float xA[6];
#pragma unroll
    for (int j = 0; j < 6; ++j) xA[j] = xs[lmA * 6 + j];

    float E[6][4];
#pragma unroll
    for (int i = 0; i < 6; ++i)
#pragma unroll
        for (int tm = 0; tm < 4; ++tm) {
            float d = xA[i] - cenv[i][tm];
            E[i][tm] = __expf(-d * d * invv[i][tm]);
        }
    float den_local = (E[0][0] + E[0][1] + E[0][2] + E[0][3])
                    * (E[1][0] + E[1][1] + E[1][2] + E[1][3])
                    * (E[2][0] + E[2][1] + E[2][2] + E[2][3])
                    * (E[3][0] + E[3][1] + E[3][2] + E[3][3])
                    * (E[4][0] + E[4][1] + E[4][2] + E[4][3])
                    * (E[5][0] + E[5][1] + E[5][2] + E[5][3]);

    float e5q = sel4(E[5][0], E[5][1], E[5][2], E[5][3], q);
    float pt16[16];
#pragma unroll
    for (int kt = 0; kt < 16; ++kt)
        pt16[kt] = E[3][kt >> 2] * E[4][kt & 3] * e5q;   // digits: kt>>2, kt&3, q

    // PH[row=wv*16+q*4+r][h=nt*16+t]: digits (nt, t>>2, t&3)
    float PH16[4][4];
    {
        const int tm1 = t >> 2, tm2 = t & 3;
        float c1 = sel4(cenv[1][0], cenv[1][1], cenv[1][2], cenv[1][3], tm1);
        float i1 = sel4(invv[1][0], invv[1][1], invv[1][2], invv[1][3], tm1);
        float c2 = sel4(cenv[2][0], cenv[2][1], cenv[2][2], cenv[2][3], tm2);
        float i2 = sel4(invv[2][0], invv[2][1], invv[2][2], invv[2][3], tm2);
#pragma unroll
        for (int r = 0; r < 4; ++r) {
            int lr = wv * 16 + q * 4 + r;
            float x0 = xs[lr * 6 + 0];
            float x1 = xs[lr * 6 + 1];
            float x2 = xs[lr * 6 + 2];
            float d1 = x1 - c1, d2 = x2 - c2;
            float G12 = __expf(-d1 * d1 * i1) * __expf(-d2 * d2 * i2);
#pragma unroll
            for (int nt = 0; nt < 4; ++nt) {
                float d0 = x0 - cenv[0][nt];
                PH16[r][nt] = G12 * __expf(-d0 * d0 * invv[0][nt]);
            }
        }
    }

    float xa[6];
#pragma unroll
    for (int j = 0; j < 6; ++j) xa[j] = xA[j];

    __syncthreads();                      // tab ready (cross-wave coverage)

    // ---- GEMM: V[16][64] = U[16][512] @ Bm[512][64], fp16, 4 MFMA/kt ----
    union U4 { unsigned int u[4]; f16x8 v; };
    f32x4 Dn[8];                          // [kt&1][nt] accumulator split
#pragma unroll
    for (int a = 0; a < 8; ++a) Dn[a] = (f32x4){0.f, 0.f, 0.f, 0.f};

#pragma unroll 4
    for (int kt = 0; kt < 16; ++kt) {
        const uint4* base = &tab[(kt * 4 + q) * TAB_STR + t];
        U4 Bf[4];
#pragma unroll
        for (int nt = 0; nt < 4; ++nt) {
            uint4 bw = base[nt * 16];     // b128, 8-way floor, pad-65
            Bf[nt].u[0] = bw.x; Bf[nt].u[1] = bw.y;
            Bf[nt].u[2] = bw.z; Bf[nt].u[3] = bw.w;
        }
        float ptv = pt16[kt];
        U4 Af;
        Af.u[0] = pkh(ptv * xa[0], ptv * xa[1]);
        Af.u[1] = pkh(ptv * xa[2], ptv * xa[3]);
        Af.u[2] = pkh(ptv * xa[4], ptv * xa[5]);
        Af.u[3] = pkh(ptv, 0.f);          // xaug[6]=1, xaug[7]=0
        const int ab = (kt & 1) * 4;
#pragma unroll
        for (int nt = 0; nt < 4; ++nt)
            Dn[ab + nt] = __builtin_amdgcn_mfma_f32_16x16x32_f16(
                Af.v, Bf[nt].v, Dn[ab + nt], 0, 0, 0);
    }

    // ---- epilogue: Pn[r] = sum_n PH*V (t-reduction); den via shuffle ----
    float Pn[4] = {0.f, 0.f, 0.f, 0.f};
#pragma unroll
    for (int nt = 0; nt < 4; ++nt)
#pragma unroll
        for (int r = 0; r < 4; ++r)
            Pn[r] = fmaf(PH16[r][nt], Dn[nt][r] + Dn[4 + nt][r], Pn[r]);
#pragma unroll
    for (int off = 1; off < 16; off <<= 1)
#pragma unroll
        for (int r = 0; r < 4; ++r)
            Pn[r] += __shfl_xor(Pn[r], off);

    float dq[4];
#pragma unroll
    for (int r = 0; r < 4; ++r)
        dq[r] = __shfl(den_local, q * 4 + r);   // den of row wv*16+q*4+r

    if (t == 0) {
        long bo = blockbase + wv * 16 + q * 4;
        float o[4];
#pragma unroll
        for (int r = 0; r < 4; ++r) o[r] = Pn[r] / (dq[r] + 1e-8f);
        if (bo + 3 < B) {
            *(float4*)&out[bo] = make_float4(o[0], o[1], o[2], o[3]);
        } else {
#pragma unroll
            for (int r = 0; r < 4; ++r)
                if (bo + r < B) out[bo + r] = o[r];
        }
    }
}

extern "C" void kernel_launch(void* const* d_in, const int* in_sizes, int n_in,
                              void* d_out, int out_size, void* d_ws, size_t ws_size,
                              hipStream_t stream) {
    const float* x       = (const float*)d_in[0];
    const float* centers = (const float*)d_in[1];
    const float* sigmas  = (const float*)d_in[2];
    const float* cons    = (const float*)d_in[3];
    float* out = (float*)d_out;

    int B = in_sizes[0] / 6;                       // 32768
    (void)hipFuncSetAttribute(reinterpret_cast<const void*>(anfis_one),
                              hipFuncAttributeMaxDynamicSharedMemorySize,
                              TAB_BYTES);
    int blocks = (B + 63) / 64;                    // 512
    anfis_one<<<blocks, THREADS, TAB_BYTES, stream>>>(x, centers, sigmas, cons,
                                                      out, B);
}